// Round 17
// baseline (237.887 us; speedup 1.0000x reference)
//
#include <hip/hip_runtime.h>
#include <hip/hip_bf16.h>

#define N_NODES 50000
#define N_EDGES 800000
#define HID 128
#define SCAN_B 196      // ceil(50000/256)
#define NPROJ 391       // ceil(50000/128) projp tiles
#define NPERM 782       // ceil(800000/1024) permute chunks

typedef __bf16 bf16x8 __attribute__((ext_vector_type(8)));
typedef float f32x4 __attribute__((ext_vector_type(4)));

// ---------------------------------------------------------------------------
// prep: blocks [0,256) repack weights into MFMA-B-fragment-major bf16;
//       blocks [256,...) histogram edge dst. (proven R13)
// ---------------------------------------------------------------------------
__global__ __launch_bounds__(256) void prep_kernel(
    const float* __restrict__ Win, const float* __restrict__ W1,
    const float* __restrict__ W2, __bf16* __restrict__ Wsw,
    const int* __restrict__ eidx, int* __restrict__ hist)
{
    int b = blockIdx.x;
    int tid = threadIdx.x;
    if (b < 256) {
        int id = b * 256 + tid;   // 0..65535
        int m     = id >> 14;
        int rem   = id & 16383;
        int j     = rem & 7;
        int lane  = (rem >> 3) & 63;
        int ntile = (rem >> 9) & 7;
        int kstep = rem >> 12;
        int k = kstep * 32 + (lane >> 4) * 8 + j;
        int n = ntile * 16 + (lane & 15);
        float v;
        if (m == 0)      v = Win[k * HID + n];
        else if (m == 1) v = W1[k * HID + n];
        else if (m == 2) v = W1[(k + HID) * HID + n];
        else             v = W2[k * HID + n];
        Wsw[id] = (__bf16)v;
    } else {
        int e = (b - 256) * 256 + tid;
        if (e < N_EDGES) atomicAdd(&hist[eidx[N_EDGES + e]], 1);
    }
}

// ---------------------------------------------------------------------------
// scan: single kernel, 196 blocks (co-resident), proven R15/R16.
// ---------------------------------------------------------------------------
__global__ __launch_bounds__(256) void scan_kernel(
    const int* __restrict__ hist, int* __restrict__ bsum,
    int* __restrict__ offs, int* __restrict__ cursor)
{
    __shared__ int s[256];
    int b = blockIdx.x, tid = threadIdx.x;
    int i = b * 256 + tid;
    int v = (i < N_NODES) ? hist[i] : 0;
    s[tid] = v;
    __syncthreads();
    for (int d = 1; d < 256; d <<= 1) {
        int tv = (tid >= d) ? s[tid - d] : 0;
        __syncthreads();
        s[tid] += tv;
        __syncthreads();
    }
    int inc = s[tid];
    int total = s[255];
    __syncthreads();

    if (tid == 0)
        __hip_atomic_store(&bsum[b], total + 1, __ATOMIC_RELEASE, __HIP_MEMORY_SCOPE_AGENT);

    int pv = 0;
    if (tid < b) {
        int t;
        while ((t = __hip_atomic_load(&bsum[tid], __ATOMIC_ACQUIRE, __HIP_MEMORY_SCOPE_AGENT)) == 0)
            __builtin_amdgcn_s_sleep(1);
        pv = t - 1;
    }
    s[tid] = pv;
    __syncthreads();
    for (int d = 128; d >= 1; d >>= 1) {
        if (tid < d) s[tid] += s[tid + d];
        __syncthreads();
    }
    int pre = s[0];
    if (i < N_NODES) {
        int o = inc - v + pre;
        offs[i] = o;
        cursor[i] = o;
    }
}

// ---------------------------------------------------------------------------
// mega: blocks [0,NPROJ) = projp tile; blocks [NPROJ,NPROJ+NPERM) = permute
// chunks (single pass, 1024 edges each). Data-independent halves co-reside.
// (proven R13; plain stores — nt gave no benefit, R16)
// ---------------------------------------------------------------------------
__global__ __launch_bounds__(256) void mega_kernel(
    const float* __restrict__ x, const __bf16* __restrict__ Wsw,
    const float* __restrict__ b_in, const float* __restrict__ b1,
    float* __restrict__ P1a, __bf16* __restrict__ P1b,
    const int* __restrict__ eidx, int* __restrict__ cursor,
    unsigned short* __restrict__ srt)
{
    int bb = blockIdx.x;
    int tid = threadIdx.x;

    if (bb >= NPROJ) {
        // ---- permute: one 1024-edge chunk ----
        int e0 = (bb - NPROJ) * 1024;
        int d[4], s[4], p[4];
        bool ok[4];
#pragma unroll
        for (int k = 0; k < 4; ++k) {
            int e = e0 + k * 256 + tid;
            ok[k] = e < N_EDGES;
            if (ok[k]) {
                d[k] = eidx[N_EDGES + e];
                s[k] = eidx[e];
            }
        }
#pragma unroll
        for (int k = 0; k < 4; ++k)
            if (ok[k]) p[k] = atomicAdd(&cursor[d[k]], 1);
#pragma unroll
        for (int k = 0; k < 4; ++k)
            if (ok[k]) srt[p[k]] = (unsigned short)s[k];
        return;
    }

    // ---- projp ----
    __shared__ __bf16 At[128][136];
    int wave = tid >> 6, lane = tid & 63;
    int r_lane = lane & 15, quad = lane >> 4;
    int m0 = bb * 128;

    for (int i = tid; i < 128 * 32; i += 256) {
        int r = i >> 5, c = i & 31;
        int row = m0 + r;
        float4 v = make_float4(0.f, 0.f, 0.f, 0.f);
        if (row < N_NODES) v = *(const float4*)(x + (long)row * HID + c * 4);
        __bf16* dst = &At[r][c * 4];
        dst[0] = (__bf16)v.x; dst[1] = (__bf16)v.y;
        dst[2] = (__bf16)v.z; dst[3] = (__bf16)v.w;
    }
    __syncthreads();

    // stage 1: h = relu(x @ W_in + b_in), in place
    {
        f32x4 acc[2][8] = {};
#pragma unroll
        for (int ks = 0; ks < 4; ++ks) {
            int kb = ks * 32 + quad * 8;
            bf16x8 a0 = *(const bf16x8*)(&At[wave * 32 + r_lane][kb]);
            bf16x8 a1 = *(const bf16x8*)(&At[wave * 32 + 16 + r_lane][kb]);
#pragma unroll
            for (int n = 0; n < 8; ++n) {
                bf16x8 b = *(const bf16x8*)(Wsw + ((ks * 8 + n) * 64 + lane) * 8);
                acc[0][n] = __builtin_amdgcn_mfma_f32_16x16x32_bf16(a0, b, acc[0][n], 0, 0, 0);
                acc[1][n] = __builtin_amdgcn_mfma_f32_16x16x32_bf16(a1, b, acc[1][n], 0, 0, 0);
            }
        }
#pragma unroll
        for (int n = 0; n < 8; ++n) {
            int col = n * 16 + r_lane;
            float bias = b_in[col];
#pragma unroll
            for (int mt = 0; mt < 2; ++mt) {
                int rb = wave * 32 + mt * 16 + quad * 4;
#pragma unroll
                for (int r = 0; r < 4; ++r) {
                    float v = acc[mt][n][r] + bias;
                    At[rb + r][col] = (__bf16)(v > 0.f ? v : 0.f);
                }
            }
        }
    }
    __syncthreads();

    // stage 2a: P1a = h @ W1a + b1 (f32)
    {
        const __bf16* W1a = Wsw + 16384;
        f32x4 acc[2][8] = {};
#pragma unroll
        for (int ks = 0; ks < 4; ++ks) {
            int kb = ks * 32 + quad * 8;
            bf16x8 a0 = *(const bf16x8*)(&At[wave * 32 + r_lane][kb]);
            bf16x8 a1 = *(const bf16x8*)(&At[wave * 32 + 16 + r_lane][kb]);
#pragma unroll
            for (int n = 0; n < 8; ++n) {
                bf16x8 b = *(const bf16x8*)(W1a + ((ks * 8 + n) * 64 + lane) * 8);
                acc[0][n] = __builtin_amdgcn_mfma_f32_16x16x32_bf16(a0, b, acc[0][n], 0, 0, 0);
                acc[1][n] = __builtin_amdgcn_mfma_f32_16x16x32_bf16(a1, b, acc[1][n], 0, 0, 0);
            }
        }
#pragma unroll
        for (int n = 0; n < 8; ++n) {
            int col = n * 16 + r_lane;
            float bias = b1[col];
#pragma unroll
            for (int mt = 0; mt < 2; ++mt) {
                int rbase = m0 + wave * 32 + mt * 16 + quad * 4;
#pragma unroll
                for (int r = 0; r < 4; ++r) {
                    int row = rbase + r;
                    if (row < N_NODES)
                        P1a[(long)row * HID + col] = acc[mt][n][r] + bias;
                }
            }
        }
    }

    // stage 2b: P1b = h @ W1b (bf16)
    {
        const __bf16* W1b = Wsw + 32768;
        f32x4 acc[2][8] = {};
#pragma unroll
        for (int ks = 0; ks < 4; ++ks) {
            int kb = ks * 32 + quad * 8;
            bf16x8 a0 = *(const bf16x8*)(&At[wave * 32 + r_lane][kb]);
            bf16x8 a1 = *(const bf16x8*)(&At[wave * 32 + 16 + r_lane][kb]);
#pragma unroll
            for (int n = 0; n < 8; ++n) {
                bf16x8 b = *(const bf16x8*)(W1b + ((ks * 8 + n) * 64 + lane) * 8);
                acc[0][n] = __builtin_amdgcn_mfma_f32_16x16x32_bf16(a0, b, acc[0][n], 0, 0, 0);
                acc[1][n] = __builtin_amdgcn_mfma_f32_16x16x32_bf16(a1, b, acc[1][n], 0, 0, 0);
            }
        }
#pragma unroll
        for (int n = 0; n < 8; ++n) {
            int col = n * 16 + r_lane;
#pragma unroll
            for (int mt = 0; mt < 2; ++mt) {
                int rbase = m0 + wave * 32 + mt * 16 + quad * 4;
#pragma unroll
                for (int r = 0; r < 4; ++r) {
                    int row = rbase + r;
                    if (row < N_NODES)
                        P1b[(long)row * HID + col] = (__bf16)acc[mt][n][r];
                }
            }
        }
    }
}

// ---------------------------------------------------------------------------
// 8 relu-accumulates of one P1b row (8 bf16 in uint4) against P1a (f32x8)
// ---------------------------------------------------------------------------
__device__ inline void acc8(float4& rA, float4& rB,
                            const float4 paA, const float4 paB, uint4 q)
{
    float t;
    t = paA.x + __uint_as_float(q.x << 16);         rA.x += t > 0.f ? t : 0.f;
    t = paA.y + __uint_as_float(q.x & 0xffff0000u); rA.y += t > 0.f ? t : 0.f;
    t = paA.z + __uint_as_float(q.y << 16);         rA.z += t > 0.f ? t : 0.f;
    t = paA.w + __uint_as_float(q.y & 0xffff0000u); rA.w += t > 0.f ? t : 0.f;
    t = paB.x + __uint_as_float(q.z << 16);         rB.x += t > 0.f ? t : 0.f;
    t = paB.y + __uint_as_float(q.z & 0xffff0000u); rB.y += t > 0.f ? t : 0.f;
    t = paB.z + __uint_as_float(q.w << 16);         rB.z += t > 0.f ? t : 0.f;
    t = paB.w + __uint_as_float(q.w & 0xffff0000u); rB.w += t > 0.f ? t : 0.f;
}

// ---------------------------------------------------------------------------
// aggnode v5: 128 nodes/block, 1024 thr (16 waves). Continues the proven
// geometry gradient (256/64n: 65us < 512/64n: 65us < 512/128n: 51us):
// more waves/block -> more resident waves/CU at grid ~1.5 blocks/CU.
// Phase 1: 64 teams x 16 lanes; team aggregates 2 rows into LDS At (bf16),
//          x8 unrolled edge loop (8 gathers in flight/lane).
// Phase 2: waves 0-7 each own one 16-row m-tile (proven tile); 8-15 exit.
// Per-row summation order identical to R13 -> bitwise-identical output.
// ---------------------------------------------------------------------------
__global__ __launch_bounds__(1024) void aggnode_kernel(
    const float* __restrict__ P1a, const __bf16* __restrict__ P1b,
    const unsigned short* __restrict__ srt, const int* __restrict__ offs,
    const int* __restrict__ hist, const __bf16* __restrict__ Wsw,
    const float* __restrict__ b2, const float* __restrict__ Wc,
    const float* __restrict__ bc, float* __restrict__ out)
{
    __shared__ __bf16 At[128][136];
    int tid = threadIdx.x;
    int m0 = blockIdx.x * 128;

    // ---- phase 1: aggregate into At ----
    {
        int team = tid >> 4;        // 0..63
        int tl = tid & 15;          // cols [8tl, 8tl+8)
        for (int g = 0; g < 2; ++g) {
            int r = team * 2 + g;
            int node = m0 + r;
            float4 rA = make_float4(0.f, 0.f, 0.f, 0.f);
            float4 rB = make_float4(0.f, 0.f, 0.f, 0.f);
            if (node < N_NODES) {
                int beg = offs[node];
                int deg = hist[node];
                const float* par = P1a + (long)node * HID + tl * 8;
                float4 paA = *(const float4*)par;
                float4 paB = *(const float4*)(par + 4);
                int j = 0;
                for (; j + 8 <= deg; j += 8) {
                    int s0 = srt[beg + j];
                    int s1 = srt[beg + j + 1];
                    int s2 = srt[beg + j + 2];
                    int s3 = srt[beg + j + 3];
                    int s4 = srt[beg + j + 4];
                    int s5 = srt[beg + j + 5];
                    int s6 = srt[beg + j + 6];
                    int s7 = srt[beg + j + 7];
                    uint4 q0 = *(const uint4*)(P1b + (long)s0 * HID + tl * 8);
                    uint4 q1 = *(const uint4*)(P1b + (long)s1 * HID + tl * 8);
                    uint4 q2 = *(const uint4*)(P1b + (long)s2 * HID + tl * 8);
                    uint4 q3 = *(const uint4*)(P1b + (long)s3 * HID + tl * 8);
                    uint4 q4 = *(const uint4*)(P1b + (long)s4 * HID + tl * 8);
                    uint4 q5 = *(const uint4*)(P1b + (long)s5 * HID + tl * 8);
                    uint4 q6 = *(const uint4*)(P1b + (long)s6 * HID + tl * 8);
                    uint4 q7 = *(const uint4*)(P1b + (long)s7 * HID + tl * 8);
                    acc8(rA, rB, paA, paB, q0);
                    acc8(rA, rB, paA, paB, q1);
                    acc8(rA, rB, paA, paB, q2);
                    acc8(rA, rB, paA, paB, q3);
                    acc8(rA, rB, paA, paB, q4);
                    acc8(rA, rB, paA, paB, q5);
                    acc8(rA, rB, paA, paB, q6);
                    acc8(rA, rB, paA, paB, q7);
                }
                for (; j < deg; ++j) {
                    int s = srt[beg + j];
                    uint4 q = *(const uint4*)(P1b + (long)s * HID + tl * 8);
                    acc8(rA, rB, paA, paB, q);
                }
            }
            __bf16 vv[8];
            vv[0] = (__bf16)rA.x; vv[1] = (__bf16)rA.y;
            vv[2] = (__bf16)rA.z; vv[3] = (__bf16)rA.w;
            vv[4] = (__bf16)rB.x; vv[5] = (__bf16)rB.y;
            vv[6] = (__bf16)rB.z; vv[7] = (__bf16)rB.w;
            *(uint4*)(&At[r][tl * 8]) = *(uint4*)vv;
        }
    }
    __syncthreads();

    // ---- phase 2: node GEMM, waves 0-7 x one 16-row m-tile ----
    int wave = tid >> 6, lane = tid & 63;
    if (wave >= 8) return;
    int r_lane = lane & 15, quad = lane >> 4;
    const __bf16* W2f = Wsw + 49152;
    f32x4 acc[8] = {};
#pragma unroll
    for (int ks = 0; ks < 4; ++ks) {
        int kb = ks * 32 + quad * 8;
        bf16x8 a0 = *(const bf16x8*)(&At[wave * 16 + r_lane][kb]);
#pragma unroll
        for (int n = 0; n < 8; ++n) {
            bf16x8 b = *(const bf16x8*)(W2f + ((ks * 8 + n) * 64 + lane) * 8);
            acc[n] = __builtin_amdgcn_mfma_f32_16x16x32_bf16(a0, b, acc[n], 0, 0, 0);
        }
    }

#pragma unroll
    for (int r = 0; r < 4; ++r) {
        int row = m0 + wave * 16 + quad * 4 + r;
        float deg = (row < N_NODES) ? (float)hist[row] : 0.f;
        float s0 = 0.f, s1 = 0.f;
#pragma unroll
        for (int n = 0; n < 8; ++n) {
            int col = n * 16 + r_lane;
            float v = acc[n][r] + deg * b2[col];
            v = v > 0.f ? v : 0.f;
            s0 += v * Wc[col * 2 + 0];
            s1 += v * Wc[col * 2 + 1];
        }
#pragma unroll
        for (int off = 1; off < 16; off <<= 1) {
            s0 += __shfl_xor(s0, off);
            s1 += __shfl_xor(s1, off);
        }
        if (r_lane == 0 && row < N_NODES) {
            out[(long)row * 2 + 0] = s0 + bc[0];
            out[(long)row * 2 + 1] = s1 + bc[1];
        }
    }
}

extern "C" void kernel_launch(void* const* d_in, const int* in_sizes, int n_in,
                              void* d_out, int out_size, void* d_ws, size_t ws_size,
                              hipStream_t stream) {
    const float* x    = (const float*)d_in[0];
    const int* eidx   = (const int*)d_in[1];
    const float* W_in = (const float*)d_in[2];
    const float* b_in = (const float*)d_in[3];
    const float* W1   = (const float*)d_in[4];
    const float* b1   = (const float*)d_in[5];
    const float* W2   = (const float*)d_in[6];
    const float* b2   = (const float*)d_in[7];
    const float* Wc   = (const float*)d_in[8];
    const float* bc   = (const float*)d_in[9];
    float* out = (float*)d_out;

    char* ws = (char*)d_ws;
    float*  P1a  = (float*)(ws + 0);                        // 25,600,000
    __bf16* P1b  = (__bf16*)(ws + 25600000);                // 12,800,000
    unsigned short* srt = (unsigned short*)(ws + 38400000); //  1,600,000
    int* hist    = (int*)(ws + 41600000);                   //    200,000
    int* bsum    = (int*)(ws + 41800000);                   //      1,024 (contiguous w/ hist: one memset)
    int* offs    = (int*)(ws + 42000000);                   //    200,000
    int* cursor  = (int*)(ws + 42200000);                   //    200,000
    __bf16* Wsw  = (__bf16*)(ws + 42401024);                //    131,072

    // one memset covers hist (200000 B) + bsum (1024 B)
    hipMemsetAsync(hist, 0, 200000 + 1024, stream);

    prep_kernel<<<256 + (N_EDGES + 255) / 256, 256, 0, stream>>>(W_in, W1, W2, Wsw, eidx, hist);
    scan_kernel<<<SCAN_B, 256, 0, stream>>>(hist, bsum, offs, cursor);
    mega_kernel<<<NPROJ + NPERM, 256, 0, stream>>>(x, Wsw, b_in, b1, P1a, P1b,
                                                   eidx, cursor, srt);
    aggnode_kernel<<<(N_NODES + 127) / 128, 1024, 0, stream>>>(
        P1a, P1b, srt, offs, hist, Wsw, b2, Wc, bc, out);
}

// Round 18
// 230.683 us; speedup vs baseline: 1.0312x; 1.0312x over previous
//
#include <hip/hip_runtime.h>
#include <hip/hip_bf16.h>

#define N_NODES 50000
#define N_EDGES 800000
#define HID 128
#define SCAN_B 196      // ceil(50000/256)
#define NPROJ 391       // ceil(50000/128) projp tiles
#define NPERM 3125      // 800000/256 permute chunks (1 edge/thread)

typedef __bf16 bf16x8 __attribute__((ext_vector_type(8)));
typedef float f32x4 __attribute__((ext_vector_type(4)));

// ---------------------------------------------------------------------------
// prep: blocks [0,256) repack weights into MFMA-B-fragment-major bf16;
//       blocks [256,...) histogram edge dst. (proven R13)
// ---------------------------------------------------------------------------
__global__ __launch_bounds__(256) void prep_kernel(
    const float* __restrict__ Win, const float* __restrict__ W1,
    const float* __restrict__ W2, __bf16* __restrict__ Wsw,
    const int* __restrict__ eidx, int* __restrict__ hist)
{
    int b = blockIdx.x;
    int tid = threadIdx.x;
    if (b < 256) {
        int id = b * 256 + tid;   // 0..65535
        int m     = id >> 14;
        int rem   = id & 16383;
        int j     = rem & 7;
        int lane  = (rem >> 3) & 63;
        int ntile = (rem >> 9) & 7;
        int kstep = rem >> 12;
        int k = kstep * 32 + (lane >> 4) * 8 + j;
        int n = ntile * 16 + (lane & 15);
        float v;
        if (m == 0)      v = Win[k * HID + n];
        else if (m == 1) v = W1[k * HID + n];
        else if (m == 2) v = W1[(k + HID) * HID + n];
        else             v = W2[k * HID + n];
        Wsw[id] = (__bf16)v;
    } else {
        int e = (b - 256) * 256 + tid;
        if (e < N_EDGES) atomicAdd(&hist[eidx[N_EDGES + e]], 1);
    }
}

// ---------------------------------------------------------------------------
// scan: single kernel, 196 blocks (co-resident), proven R15/R16.
// ---------------------------------------------------------------------------
__global__ __launch_bounds__(256) void scan_kernel(
    const int* __restrict__ hist, int* __restrict__ bsum,
    int* __restrict__ offs, int* __restrict__ cursor)
{
    __shared__ int s[256];
    int b = blockIdx.x, tid = threadIdx.x;
    int i = b * 256 + tid;
    int v = (i < N_NODES) ? hist[i] : 0;
    s[tid] = v;
    __syncthreads();
    for (int d = 1; d < 256; d <<= 1) {
        int tv = (tid >= d) ? s[tid - d] : 0;
        __syncthreads();
        s[tid] += tv;
        __syncthreads();
    }
    int inc = s[tid];
    int total = s[255];
    __syncthreads();

    if (tid == 0)
        __hip_atomic_store(&bsum[b], total + 1, __ATOMIC_RELEASE, __HIP_MEMORY_SCOPE_AGENT);

    int pv = 0;
    if (tid < b) {
        int t;
        while ((t = __hip_atomic_load(&bsum[tid], __ATOMIC_ACQUIRE, __HIP_MEMORY_SCOPE_AGENT)) == 0)
            __builtin_amdgcn_s_sleep(1);
        pv = t - 1;
    }
    s[tid] = pv;
    __syncthreads();
    for (int d = 128; d >= 1; d >>= 1) {
        if (tid < d) s[tid] += s[tid + d];
        __syncthreads();
    }
    int pre = s[0];
    if (i < N_NODES) {
        int o = inc - v + pre;
        offs[i] = o;
        cursor[i] = o;
    }
}

// ---------------------------------------------------------------------------
// mega: blocks [0,NPROJ) = projp tile; blocks [NPROJ,NPROJ+NPERM) = permute
// chunks (256 edges each, 1 edge/thread -> ~4x scatter waves in flight vs
// the 4-edge/thread variant). Data-independent halves co-reside.
// ---------------------------------------------------------------------------
__global__ __launch_bounds__(256) void mega_kernel(
    const float* __restrict__ x, const __bf16* __restrict__ Wsw,
    const float* __restrict__ b_in, const float* __restrict__ b1,
    float* __restrict__ P1a, __bf16* __restrict__ P1b,
    const int* __restrict__ eidx, int* __restrict__ cursor,
    unsigned short* __restrict__ srt)
{
    int bb = blockIdx.x;
    int tid = threadIdx.x;

    if (bb >= NPROJ) {
        // ---- permute: one 256-edge chunk, 1 edge/thread ----
        int e = (bb - NPROJ) * 256 + tid;
        if (e < N_EDGES) {
            int d = eidx[N_EDGES + e];
            int s = eidx[e];
            int p = atomicAdd(&cursor[d], 1);
            srt[p] = (unsigned short)s;
        }
        return;
    }

    // ---- projp ----
    __shared__ __bf16 At[128][136];
    int wave = tid >> 6, lane = tid & 63;
    int r_lane = lane & 15, quad = lane >> 4;
    int m0 = bb * 128;

    for (int i = tid; i < 128 * 32; i += 256) {
        int r = i >> 5, c = i & 31;
        int row = m0 + r;
        float4 v = make_float4(0.f, 0.f, 0.f, 0.f);
        if (row < N_NODES) v = *(const float4*)(x + (long)row * HID + c * 4);
        __bf16* dst = &At[r][c * 4];
        dst[0] = (__bf16)v.x; dst[1] = (__bf16)v.y;
        dst[2] = (__bf16)v.z; dst[3] = (__bf16)v.w;
    }
    __syncthreads();

    // stage 1: h = relu(x @ W_in + b_in), in place
    {
        f32x4 acc[2][8] = {};
#pragma unroll
        for (int ks = 0; ks < 4; ++ks) {
            int kb = ks * 32 + quad * 8;
            bf16x8 a0 = *(const bf16x8*)(&At[wave * 32 + r_lane][kb]);
            bf16x8 a1 = *(const bf16x8*)(&At[wave * 32 + 16 + r_lane][kb]);
#pragma unroll
            for (int n = 0; n < 8; ++n) {
                bf16x8 b = *(const bf16x8*)(Wsw + ((ks * 8 + n) * 64 + lane) * 8);
                acc[0][n] = __builtin_amdgcn_mfma_f32_16x16x32_bf16(a0, b, acc[0][n], 0, 0, 0);
                acc[1][n] = __builtin_amdgcn_mfma_f32_16x16x32_bf16(a1, b, acc[1][n], 0, 0, 0);
            }
        }
#pragma unroll
        for (int n = 0; n < 8; ++n) {
            int col = n * 16 + r_lane;
            float bias = b_in[col];
#pragma unroll
            for (int mt = 0; mt < 2; ++mt) {
                int rb = wave * 32 + mt * 16 + quad * 4;
#pragma unroll
                for (int r = 0; r < 4; ++r) {
                    float v = acc[mt][n][r] + bias;
                    At[rb + r][col] = (__bf16)(v > 0.f ? v : 0.f);
                }
            }
        }
    }
    __syncthreads();

    // stage 2a: P1a = h @ W1a + b1 (f32)
    {
        const __bf16* W1a = Wsw + 16384;
        f32x4 acc[2][8] = {};
#pragma unroll
        for (int ks = 0; ks < 4; ++ks) {
            int kb = ks * 32 + quad * 8;
            bf16x8 a0 = *(const bf16x8*)(&At[wave * 32 + r_lane][kb]);
            bf16x8 a1 = *(const bf16x8*)(&At[wave * 32 + 16 + r_lane][kb]);
#pragma unroll
            for (int n = 0; n < 8; ++n) {
                bf16x8 b = *(const bf16x8*)(W1a + ((ks * 8 + n) * 64 + lane) * 8);
                acc[0][n] = __builtin_amdgcn_mfma_f32_16x16x32_bf16(a0, b, acc[0][n], 0, 0, 0);
                acc[1][n] = __builtin_amdgcn_mfma_f32_16x16x32_bf16(a1, b, acc[1][n], 0, 0, 0);
            }
        }
#pragma unroll
        for (int n = 0; n < 8; ++n) {
            int col = n * 16 + r_lane;
            float bias = b1[col];
#pragma unroll
            for (int mt = 0; mt < 2; ++mt) {
                int rbase = m0 + wave * 32 + mt * 16 + quad * 4;
#pragma unroll
                for (int r = 0; r < 4; ++r) {
                    int row = rbase + r;
                    if (row < N_NODES)
                        P1a[(long)row * HID + col] = acc[mt][n][r] + bias;
                }
            }
        }
    }

    // stage 2b: P1b = h @ W1b (bf16)
    {
        const __bf16* W1b = Wsw + 32768;
        f32x4 acc[2][8] = {};
#pragma unroll
        for (int ks = 0; ks < 4; ++ks) {
            int kb = ks * 32 + quad * 8;
            bf16x8 a0 = *(const bf16x8*)(&At[wave * 32 + r_lane][kb]);
            bf16x8 a1 = *(const bf16x8*)(&At[wave * 32 + 16 + r_lane][kb]);
#pragma unroll
            for (int n = 0; n < 8; ++n) {
                bf16x8 b = *(const bf16x8*)(W1b + ((ks * 8 + n) * 64 + lane) * 8);
                acc[0][n] = __builtin_amdgcn_mfma_f32_16x16x32_bf16(a0, b, acc[0][n], 0, 0, 0);
                acc[1][n] = __builtin_amdgcn_mfma_f32_16x16x32_bf16(a1, b, acc[1][n], 0, 0, 0);
            }
        }
#pragma unroll
        for (int n = 0; n < 8; ++n) {
            int col = n * 16 + r_lane;
#pragma unroll
            for (int mt = 0; mt < 2; ++mt) {
                int rbase = m0 + wave * 32 + mt * 16 + quad * 4;
#pragma unroll
                for (int r = 0; r < 4; ++r) {
                    int row = rbase + r;
                    if (row < N_NODES)
                        P1b[(long)row * HID + col] = (__bf16)acc[mt][n][r];
                }
            }
        }
    }
}

// ---------------------------------------------------------------------------
// 8 relu-accumulates of one P1b row (8 bf16 in uint4) against P1a (f32x8)
// ---------------------------------------------------------------------------
__device__ inline void acc8(float4& rA, float4& rB,
                            const float4 paA, const float4 paB, uint4 q)
{
    float t;
    t = paA.x + __uint_as_float(q.x << 16);         rA.x += t > 0.f ? t : 0.f;
    t = paA.y + __uint_as_float(q.x & 0xffff0000u); rA.y += t > 0.f ? t : 0.f;
    t = paA.z + __uint_as_float(q.y << 16);         rA.z += t > 0.f ? t : 0.f;
    t = paA.w + __uint_as_float(q.y & 0xffff0000u); rA.w += t > 0.f ? t : 0.f;
    t = paB.x + __uint_as_float(q.z << 16);         rB.x += t > 0.f ? t : 0.f;
    t = paB.y + __uint_as_float(q.z & 0xffff0000u); rB.y += t > 0.f ? t : 0.f;
    t = paB.z + __uint_as_float(q.w << 16);         rB.z += t > 0.f ? t : 0.f;
    t = paB.w + __uint_as_float(q.w & 0xffff0000u); rB.w += t > 0.f ? t : 0.f;
}

// ---------------------------------------------------------------------------
// aggnode (R13-proven exact, 51us best): fused CSR aggregation + node finish.
// Block = 128 nodes, 512 thr. Phase 1: 32 teams x 16 lanes, 4 rows/team,
// edge loop unrolled x8 (8 gathers in flight/lane), At (bf16) in LDS.
// Phase 2: 8 waves, wave w owns 16-row m-tile:
//   h2 = relu(At @ W2 + deg*b2); out = h2 @ Wc + bc
// ---------------------------------------------------------------------------
__global__ __launch_bounds__(512) void aggnode_kernel(
    const float* __restrict__ P1a, const __bf16* __restrict__ P1b,
    const unsigned short* __restrict__ srt, const int* __restrict__ offs,
    const int* __restrict__ hist, const __bf16* __restrict__ Wsw,
    const float* __restrict__ b2, const float* __restrict__ Wc,
    const float* __restrict__ bc, float* __restrict__ out)
{
    __shared__ __bf16 At[128][136];
    int tid = threadIdx.x;
    int m0 = blockIdx.x * 128;

    // ---- phase 1: aggregate into At ----
    {
        int team = tid >> 4;        // 0..31
        int tl = tid & 15;          // cols [8tl, 8tl+8)
        for (int g = 0; g < 4; ++g) {
            int r = team * 4 + g;
            int node = m0 + r;
            float4 rA = make_float4(0.f, 0.f, 0.f, 0.f);
            float4 rB = make_float4(0.f, 0.f, 0.f, 0.f);
            if (node < N_NODES) {
                int beg = offs[node];
                int deg = hist[node];
                const float* par = P1a + (long)node * HID + tl * 8;
                float4 paA = *(const float4*)par;
                float4 paB = *(const float4*)(par + 4);
                int j = 0;
                for (; j + 8 <= deg; j += 8) {
                    int s0 = srt[beg + j];
                    int s1 = srt[beg + j + 1];
                    int s2 = srt[beg + j + 2];
                    int s3 = srt[beg + j + 3];
                    int s4 = srt[beg + j + 4];
                    int s5 = srt[beg + j + 5];
                    int s6 = srt[beg + j + 6];
                    int s7 = srt[beg + j + 7];
                    uint4 q0 = *(const uint4*)(P1b + (long)s0 * HID + tl * 8);
                    uint4 q1 = *(const uint4*)(P1b + (long)s1 * HID + tl * 8);
                    uint4 q2 = *(const uint4*)(P1b + (long)s2 * HID + tl * 8);
                    uint4 q3 = *(const uint4*)(P1b + (long)s3 * HID + tl * 8);
                    uint4 q4 = *(const uint4*)(P1b + (long)s4 * HID + tl * 8);
                    uint4 q5 = *(const uint4*)(P1b + (long)s5 * HID + tl * 8);
                    uint4 q6 = *(const uint4*)(P1b + (long)s6 * HID + tl * 8);
                    uint4 q7 = *(const uint4*)(P1b + (long)s7 * HID + tl * 8);
                    acc8(rA, rB, paA, paB, q0);
                    acc8(rA, rB, paA, paB, q1);
                    acc8(rA, rB, paA, paB, q2);
                    acc8(rA, rB, paA, paB, q3);
                    acc8(rA, rB, paA, paB, q4);
                    acc8(rA, rB, paA, paB, q5);
                    acc8(rA, rB, paA, paB, q6);
                    acc8(rA, rB, paA, paB, q7);
                }
                for (; j < deg; ++j) {
                    int s = srt[beg + j];
                    uint4 q = *(const uint4*)(P1b + (long)s * HID + tl * 8);
                    acc8(rA, rB, paA, paB, q);
                }
            }
            __bf16 vv[8];
            vv[0] = (__bf16)rA.x; vv[1] = (__bf16)rA.y;
            vv[2] = (__bf16)rA.z; vv[3] = (__bf16)rA.w;
            vv[4] = (__bf16)rB.x; vv[5] = (__bf16)rB.y;
            vv[6] = (__bf16)rB.z; vv[7] = (__bf16)rB.w;
            *(uint4*)(&At[r][tl * 8]) = *(uint4*)vv;
        }
    }
    __syncthreads();

    // ---- phase 2: node GEMM, 8 waves x one 16-row m-tile ----
    int wave = tid >> 6, lane = tid & 63;
    int r_lane = lane & 15, quad = lane >> 4;
    const __bf16* W2f = Wsw + 49152;
    f32x4 acc[8] = {};
#pragma unroll
    for (int ks = 0; ks < 4; ++ks) {
        int kb = ks * 32 + quad * 8;
        bf16x8 a0 = *(const bf16x8*)(&At[wave * 16 + r_lane][kb]);
#pragma unroll
        for (int n = 0; n < 8; ++n) {
            bf16x8 b = *(const bf16x8*)(W2f + ((ks * 8 + n) * 64 + lane) * 8);
            acc[n] = __builtin_amdgcn_mfma_f32_16x16x32_bf16(a0, b, acc[n], 0, 0, 0);
        }
    }

#pragma unroll
    for (int r = 0; r < 4; ++r) {
        int row = m0 + wave * 16 + quad * 4 + r;
        float deg = (row < N_NODES) ? (float)hist[row] : 0.f;
        float s0 = 0.f, s1 = 0.f;
#pragma unroll
        for (int n = 0; n < 8; ++n) {
            int col = n * 16 + r_lane;
            float v = acc[n][r] + deg * b2[col];
            v = v > 0.f ? v : 0.f;
            s0 += v * Wc[col * 2 + 0];
            s1 += v * Wc[col * 2 + 1];
        }
#pragma unroll
        for (int off = 1; off < 16; off <<= 1) {
            s0 += __shfl_xor(s0, off);
            s1 += __shfl_xor(s1, off);
        }
        if (r_lane == 0 && row < N_NODES) {
            out[(long)row * 2 + 0] = s0 + bc[0];
            out[(long)row * 2 + 1] = s1 + bc[1];
        }
    }
}

extern "C" void kernel_launch(void* const* d_in, const int* in_sizes, int n_in,
                              void* d_out, int out_size, void* d_ws, size_t ws_size,
                              hipStream_t stream) {
    const float* x    = (const float*)d_in[0];
    const int* eidx   = (const int*)d_in[1];
    const float* W_in = (const float*)d_in[2];
    const float* b_in = (const float*)d_in[3];
    const float* W1   = (const float*)d_in[4];
    const float* b1   = (const float*)d_in[5];
    const float* W2   = (const float*)d_in[6];
    const float* b2   = (const float*)d_in[7];
    const float* Wc   = (const float*)d_in[8];
    const float* bc   = (const float*)d_in[9];
    float* out = (float*)d_out;

    char* ws = (char*)d_ws;
    float*  P1a  = (float*)(ws + 0);                        // 25,600,000
    __bf16* P1b  = (__bf16*)(ws + 25600000);                // 12,800,000
    unsigned short* srt = (unsigned short*)(ws + 38400000); //  1,600,000
    int* hist    = (int*)(ws + 41600000);                   //    200,000
    int* bsum    = (int*)(ws + 41800000);                   //      1,024 (contiguous w/ hist: one memset)
    int* offs    = (int*)(ws + 42000000);                   //    200,000
    int* cursor  = (int*)(ws + 42200000);                   //    200,000
    __bf16* Wsw  = (__bf16*)(ws + 42401024);                //    131,072

    // one memset covers hist (200000 B) + bsum (1024 B)
    hipMemsetAsync(hist, 0, 200000 + 1024, stream);

    prep_kernel<<<256 + (N_EDGES + 255) / 256, 256, 0, stream>>>(W_in, W1, W2, Wsw, eidx, hist);
    scan_kernel<<<SCAN_B, 256, 0, stream>>>(hist, bsum, offs, cursor);
    mega_kernel<<<NPROJ + NPERM, 256, 0, stream>>>(x, Wsw, b_in, b1, P1a, P1b,
                                                   eidx, cursor, srt);
    aggnode_kernel<<<(N_NODES + 127) / 128, 512, 0, stream>>>(
        P1a, P1b, srt, offs, hist, Wsw, b2, Wc, bc, out);
}